// Round 3
// baseline (590.870 us; speedup 1.0000x reference)
//
#include <hip/hip_runtime.h>
#include <math.h>

#define N_NODES 100000
#define N_EDGES 1600000
#define DIM 128
#define EIGD 32
#define CS_EPS 1e-8f

#define B1 1024                   // edge-pass blocks (4/CU)
#define CHUNK 1563                // ceil(N_EDGES / B1)
#define NB 391                    // ceil(N_NODES/256) blocks of 256 rows

// ---- workspace layout (bytes), total 83,619,616 ----
// deg/cur live in the first 6.4 MB, which is later overwritten by sw
// (ks_score runs after kscat, when deg/cur are dead).
static const size_t OFF_DEG    = 0;          // N int   (dead after ks1)
static const size_t OFF_CUR    = 400000;     // N int   (dead after kscat)
static const size_t OFF_SW     = 0;          // E float edge scores (written by ks_score)
static const size_t OFF_RSTAT  = 6400000;    // N float4 {m0,z0,m1,z1}
static const size_t OFF_SE     = 12800000;   // E float2 {col_bits, adj} CSR-ordered
static const size_t OFF_BSTART = 25600000;   // (NB+1) int
static const size_t OFF_BTOT   = 25601600;   // NB int
static const size_t OFF_GPART  = 25603200;   // B1 float4
static const size_t OFF_OFFS   = 25619584;   // N+1 int
static const size_t OFF_SCAL   = 26019600;   // 4 float
static const size_t OFF_KB     = 26019616;   // N*128 bf16 = 25.6 MB
static const size_t OFF_VB     = 51619616;   // N*128 bf16 = 25.6 MB
static const size_t OFF_EB     = 77219616;   // N*32  bf16 = 6.4 MB

__device__ __forceinline__ unsigned short f2bf(float f) {
    unsigned u = __float_as_uint(f);
    unsigned r = (u + 0x7fffu + ((u >> 16) & 1u)) >> 16;   // RNE
    return (unsigned short)r;
}
__device__ __forceinline__ float blo(unsigned w) { return __uint_as_float(w << 16); }
__device__ __forceinline__ float bhi(unsigned w) { return __uint_as_float(w & 0xffff0000u); }

#define K4C 3200000   // N*128/4 float4s in k (and v)
#define E4C 800000    // N*32/4  float4s in eigs

// Convert k, v, eigs to bf16 staging arrays; also zero deg (graph-safe init).
__global__ void __launch_bounds__(256) ka_cvt(
        const float* __restrict__ k, const float* __restrict__ v,
        const float* __restrict__ eigs,
        ushort* __restrict__ kb, ushort* __restrict__ vb,
        ushort* __restrict__ eb, int* __restrict__ deg) {
    int i = blockIdx.x * blockDim.x + threadIdx.x;
    if (i < N_NODES) deg[i] = 0;
    const float* src; ushort* dst; int j;
    if (i < K4C)            { src = k;    dst = kb; j = i; }
    else if (i < 2 * K4C)   { src = v;    dst = vb; j = i - K4C; }
    else if (i < 2*K4C+E4C) { src = eigs; dst = eb; j = i - 2 * K4C; }
    else return;
    float4 f = ((const float4*)src)[j];
    ushort4 o;
    o.x = f2bf(f.x); o.y = f2bf(f.y); o.z = f2bf(f.z); o.w = f2bf(f.w);
    ((ushort4*)dst)[j] = o;
}

// COO pass: per-row degree via global atomics + cosine-sim partial sums.
__global__ void __launch_bounds__(256) kdeg(
        const int* __restrict__ row, const int* __restrict__ col,
        const float* __restrict__ motif_w, const int* __restrict__ motif_ids,
        int* __restrict__ deg, float4* __restrict__ gpart) {
    __shared__ float wlds[64];
    __shared__ float red[3][4];
    const int t = threadIdx.x, b = blockIdx.x;
    if (t < 64) wlds[t] = motif_w[t];
    __syncthreads();

    const int e0 = b * CHUNK, e1 = min(N_EDGES, e0 + CHUNK);
    float sab = 0.f, saa = 0.f, sbb = 0.f;
    for (int e = e0 + t; e < e1; e += 256) {
        int r = row[e], c = col[e];
        atomicAdd(&deg[r], 1);
        float mr = wlds[motif_ids[r]], mc = wlds[motif_ids[c]];
        sab += mr * mc; saa += mr * mr; sbb += mc * mc;
    }
#pragma unroll
    for (int off = 32; off >= 1; off >>= 1) {
        sab += __shfl_xor(sab, off);
        saa += __shfl_xor(saa, off);
        sbb += __shfl_xor(sbb, off);
    }
    int lane = t & 63, wid = t >> 6;
    if (lane == 0) { red[0][wid] = sab; red[1][wid] = saa; red[2][wid] = sbb; }
    __syncthreads();
    if (t == 0) {
        float a = 0.f, bb = 0.f, cc = 0.f;
#pragma unroll
        for (int i = 0; i < 4; i++) { a += red[0][i]; bb += red[1][i]; cc += red[2][i]; }
        gpart[b] = make_float4(a, bb, cc, 0.f);
    }
}

// Per-256-row block scan of degrees -> block-local exclusive offs + block total.
__global__ void __launch_bounds__(256) ks1(
        const int* __restrict__ deg, int* __restrict__ offs,
        int* __restrict__ btot) {
    const int t = threadIdx.x, b = blockIdx.x;
    const int r = b * 256 + t;
    int v = (r < N_NODES) ? deg[r] : 0;
    __shared__ int sc[256];
    sc[t] = v;
    __syncthreads();
    for (int off = 1; off < 256; off <<= 1) {
        int w = (t >= off) ? sc[t - off] : 0;
        __syncthreads();
        sc[t] += w;
        __syncthreads();
    }
    if (r < N_NODES) offs[r] = sc[t] - v;
    if (t == 255) btot[b] = sc[255];
}

// One block: scan block totals -> bstart; cosine reduce -> scal.
__global__ void __launch_bounds__(512) ks2(
        const int* __restrict__ btot, int* __restrict__ bstart,
        const float4* __restrict__ gpart, const float* __restrict__ gamma,
        float* __restrict__ scal, int* __restrict__ offs) {
    const int t = threadIdx.x;
    __shared__ int tot[512];
    int my = (t < NB) ? btot[t] : 0;
    tot[t] = my;
    __syncthreads();
    for (int off = 1; off < 512; off <<= 1) {
        int v = (t >= off) ? tot[t - off] : 0;
        __syncthreads();
        tot[t] += v;
        __syncthreads();
    }
    if (t < NB) bstart[t] = tot[t] - my;
    if (t == NB - 1) {
        bstart[NB] = tot[t];
        offs[N_NODES] = tot[t];
    }

    float4 g0 = gpart[t];
    float4 g1 = gpart[t + 512];
    float sab = g0.x + g1.x, saa = g0.y + g1.y, sbb = g0.z + g1.z;
#pragma unroll
    for (int off = 32; off >= 1; off >>= 1) {
        sab += __shfl_xor(sab, off);
        saa += __shfl_xor(saa, off);
        sbb += __shfl_xor(sbb, off);
    }
    __shared__ float red[3][8];
    int lane = t & 63, wid = t >> 6;
    if (lane == 0) { red[0][wid] = sab; red[1][wid] = saa; red[2][wid] = sbb; }
    __syncthreads();
    if (t == 0) {
        float a = 0.f, bb = 0.f, cc = 0.f;
#pragma unroll
        for (int i = 0; i < 8; i++) { a += red[0][i]; bb += red[1][i]; cc += red[2][i]; }
        float na = sqrtf(bb); if (na < CS_EPS) na = CS_EPS;
        float nb2 = sqrtf(cc); if (nb2 < CS_EPS) nb2 = CS_EPS;
        scal[0] = gamma[0] * (a / (na * nb2));
    }
}

// Fixup: offs += bstart of the row's block; init scatter cursors.
__global__ void __launch_bounds__(256) ks3(
        int* __restrict__ offs, const int* __restrict__ bstart,
        int* __restrict__ cur) {
    const int r = blockIdx.x * 256 + threadIdx.x;
    if (r < N_NODES) {
        int o = offs[r] + bstart[r >> 8];
        offs[r] = o;
        cur[r] = o;
    }
}

// Single scatter: COO -> CSR se via global atomic cursors. No rec staging.
__global__ void __launch_bounds__(256) kscat(
        const int* __restrict__ row, const int* __restrict__ col,
        const float* __restrict__ adj, int* __restrict__ cur,
        float2* __restrict__ se) {
    const int t = threadIdx.x, b = blockIdx.x;
    const int e0 = b * CHUNK, e1 = min(N_EDGES, e0 + CHUNK);
    for (int e = e0 + t; e < e1; e += 256) {
        int r = row[e];
        int pos = atomicAdd(&cur[r], 1);
        se[pos] = make_float2(__int_as_float(col[e]), adj[e]);
    }
}

// Pass A: scores only. Gathers kb+eb; writes per-edge s0 to sw and per-row
// {m0,z0,m1,z1} to rowstat. Low VGPR, loads fully predicated.
__global__ void __launch_bounds__(256) ks_score(
        const float* __restrict__ q, const ushort* __restrict__ kb,
        const ushort* __restrict__ eb,
        const float* __restrict__ lambda0, const int* __restrict__ offs,
        const float2* __restrict__ se, const float* __restrict__ scal,
        float* __restrict__ sw, float4* __restrict__ rowstat) {
    const int tid  = threadIdx.x;
    const int lane = tid & 63;
    const int wid  = tid >> 6;
    const int r = blockIdx.x * 4 + wid;
    if (r >= N_NODES) return;
    const int l16 = lane & 15;
    const int grp = lane >> 4;
    const float inv_sqrt_d = 0.08838834764831843f; // 1/sqrt(128)

    const int start = offs[r], end = offs[r + 1];
    if (end == start) return;   // empty row: rowstat never read by kpv

    const float el0 = __expf(lambda0[0]);
    const float cs  = scal[0];

    const float4* qp = (const float4*)(q + (size_t)r * DIM);
    const float4 qa = qp[l16 * 2];
    const float4 qc = qp[l16 * 2 + 1];
    const unsigned erw = *(const unsigned*)(eb + (size_t)r * EIGD + l16 * 2);
    const float er0 = blo(erw), er1 = bhi(erw);

    const float NEG = -1e30f;   // finite sentinel: exp underflows to 0, no NaN
    float m0 = NEG, z0 = 0.f, m1 = NEG, z1 = 0.f;

    // se prefetch depth-1, predicated per group
    float2 ea_c = make_float2(0.f, 0.f);
    if (start + grp < end) ea_c = se[start + grp];

    for (int base = start; base < end; base += 4) {
        const int e = base + grp;
        const bool act = e < end;                     // group-uniform
        float2 ea_n = make_float2(0.f, 0.f);
        if (base + 4 + grp < end) ea_n = se[base + 4 + grp];

        float s0p = 0.f;
        if (act) {
            int c = __float_as_int(ea_c.x);
            const uint4 kw = *(const uint4*)(kb + (size_t)c * DIM + l16 * 8);
            const unsigned ecw = *(const unsigned*)(eb + (size_t)c * EIGD + l16 * 2);
            float x;
            x = qa.x * blo(kw.x);
            x = fmaf(qa.y, bhi(kw.x), x);
            x = fmaf(qa.z, blo(kw.y), x);
            x = fmaf(qa.w, bhi(kw.y), x);
            x = fmaf(qc.x, blo(kw.z), x);
            x = fmaf(qc.y, bhi(kw.z), x);
            x = fmaf(qc.z, blo(kw.w), x);
            x = fmaf(qc.w, bhi(kw.w), x);
            float y = er0 * blo(ecw) + er1 * bhi(ecw);
            s0p = fmaf(el0, y, x * inv_sqrt_d);
        }
        // butterfly within the 16-lane group -> group-uniform score
#pragma unroll
        for (int off = 8; off >= 1; off >>= 1) s0p += __shfl_xor(s0p, off);

        if (act) {
            if (l16 == 0) sw[e] = s0p;   // 4 consecutive floats per wave-iter
            float nm0 = fmaxf(m0, s0p);
            z0 = z0 * __expf(m0 - nm0) + __expf(s0p - nm0);
            m0 = nm0;
            float s1 = cs * ea_c.y;
            float nm1 = fmaxf(m1, s1);
            z1 = z1 * __expf(m1 - nm1) + __expf(s1 - nm1);
            m1 = nm1;
        }
        ea_c = ea_n;
    }

    // merge the 4 groups' (m,z) pairs
#pragma unroll
    for (int off = 16; off <= 32; off <<= 1) {
        float mo = __shfl_xor(m0, off), zo = __shfl_xor(z0, off);
        float M = fmaxf(m0, mo);
        z0 = z0 * __expf(m0 - M) + zo * __expf(mo - M);
        m0 = M;
        float mo1 = __shfl_xor(m1, off), zo1 = __shfl_xor(z1, off);
        float M1 = fmaxf(m1, mo1);
        z1 = z1 * __expf(m1 - M1) + zo1 * __expf(mo1 - M1);
        m1 = M1;
    }
    if (lane == 0) rowstat[r] = make_float4(m0, z0, m1, z1);
}

// Pass B: PV only. Gathers vb; final weights from sw + rowstat (exact
// two-pass softmax).
__global__ void __launch_bounds__(256) kpv(
        const ushort* __restrict__ vb, const int* __restrict__ offs,
        const float2* __restrict__ se, const float* __restrict__ sw,
        const float* __restrict__ scal, const float4* __restrict__ rowstat,
        float* __restrict__ out) {
    const int tid  = threadIdx.x;
    const int lane = tid & 63;
    const int wid  = tid >> 6;
    const int r = blockIdx.x * 4 + wid;
    if (r >= N_NODES) return;
    const int l16 = lane & 15;
    const int grp = lane >> 4;

    float2* outp = (float2*)(out + (size_t)r * DIM);
    const int start = offs[r], end = offs[r + 1];
    if (end == start) {
        outp[l16 * 4 + grp] = make_float2(0.f, 0.f);
        return;
    }
    const float cs = scal[0];
    const float4 st = rowstat[r];
    const float m0 = st.x, iz0 = 0.5f / st.y;
    const float m1 = st.z, iz1 = 0.5f / st.w;

    float a[8];
#pragma unroll
    for (int j = 0; j < 8; j++) a[j] = 0.f;

    float2 ea_c = make_float2(0.f, 0.f);
    float  sw_c = 0.f;
    if (start + grp < end) { ea_c = se[start + grp]; sw_c = sw[start + grp]; }

    for (int base = start; base < end; base += 4) {
        const int e = base + grp;
        const bool act = e < end;
        float2 ea_n = make_float2(0.f, 0.f);
        float  sw_n = 0.f;
        if (base + 4 + grp < end) { ea_n = se[base + 4 + grp]; sw_n = sw[base + 4 + grp]; }

        if (act) {
            int c = __float_as_int(ea_c.x);
            const uint4 vw = *(const uint4*)(vb + (size_t)c * DIM + l16 * 8);
            float u = __expf(sw_c - m0) * iz0 + __expf(cs * ea_c.y - m1) * iz1;
            a[0] = fmaf(u, blo(vw.x), a[0]); a[1] = fmaf(u, bhi(vw.x), a[1]);
            a[2] = fmaf(u, blo(vw.y), a[2]); a[3] = fmaf(u, bhi(vw.y), a[3]);
            a[4] = fmaf(u, blo(vw.z), a[4]); a[5] = fmaf(u, bhi(vw.z), a[5]);
            a[6] = fmaf(u, blo(vw.w), a[6]); a[7] = fmaf(u, bhi(vw.w), a[7]);
        }
        ea_c = ea_n; sw_c = sw_n;
    }

    // plain sum across the 4 groups (weights already final)
#pragma unroll
    for (int off = 16; off <= 32; off <<= 1) {
#pragma unroll
        for (int j = 0; j < 8; j++) a[j] += __shfl_xor(a[j], off);
    }
    float b0 = grp == 0 ? a[0] : grp == 1 ? a[2] : grp == 2 ? a[4] : a[6];
    float b1 = grp == 0 ? a[1] : grp == 1 ? a[3] : grp == 2 ? a[5] : a[7];
    outp[l16 * 4 + grp] = make_float2(b0, b1);
}

extern "C" void kernel_launch(void* const* d_in, const int* in_sizes, int n_in,
                              void* d_out, int out_size, void* d_ws, size_t ws_size,
                              hipStream_t stream) {
    const float* q        = (const float*)d_in[0];
    const float* k        = (const float*)d_in[1];
    const float* v        = (const float*)d_in[2];
    const float* eigs     = (const float*)d_in[3];
    const float* adj      = (const float*)d_in[4];
    const float* lambda0  = (const float*)d_in[5];
    const float* gamma    = (const float*)d_in[6];
    const float* motif_w  = (const float*)d_in[7];
    const int*   row      = (const int*)d_in[8];
    const int*   col      = (const int*)d_in[9];
    const int*   motif_ids= (const int*)d_in[10];
    float* out = (float*)d_out;

    char* ws = (char*)d_ws;
    int*    deg    = (int*)(ws + OFF_DEG);       // aliases sw region (dead by ks_score)
    int*    cur    = (int*)(ws + OFF_CUR);       // aliases sw region (dead by ks_score)
    float*  sw     = (float*)(ws + OFF_SW);
    float4* rstat  = (float4*)(ws + OFF_RSTAT);
    float2* se     = (float2*)(ws + OFF_SE);
    int*    bstart = (int*)(ws + OFF_BSTART);
    int*    btot   = (int*)(ws + OFF_BTOT);
    float4* gpart  = (float4*)(ws + OFF_GPART);
    int*    offs   = (int*)(ws + OFF_OFFS);
    float*  scal   = (float*)(ws + OFF_SCAL);
    ushort* kb     = (ushort*)(ws + OFF_KB);
    ushort* vb     = (ushort*)(ws + OFF_VB);
    ushort* eb     = (ushort*)(ws + OFF_EB);

    hipLaunchKernelGGL(ka_cvt, dim3((2 * K4C + E4C + 255) / 256), dim3(256), 0, stream,
                       k, v, eigs, kb, vb, eb, deg);
    hipLaunchKernelGGL(kdeg, dim3(B1), dim3(256), 0, stream,
                       row, col, motif_w, motif_ids, deg, gpart);
    hipLaunchKernelGGL(ks1, dim3(NB), dim3(256), 0, stream,
                       deg, offs, btot);
    hipLaunchKernelGGL(ks2, dim3(1), dim3(512), 0, stream,
                       btot, bstart, gpart, gamma, scal, offs);
    hipLaunchKernelGGL(ks3, dim3(NB), dim3(256), 0, stream,
                       offs, bstart, cur);
    hipLaunchKernelGGL(kscat, dim3(B1), dim3(256), 0, stream,
                       row, col, adj, cur, se);
    hipLaunchKernelGGL(ks_score, dim3((N_NODES + 3) / 4), dim3(256), 0, stream,
                       q, kb, eb, lambda0, offs, se, scal, sw, rstat);
    hipLaunchKernelGGL(kpv, dim3((N_NODES + 3) / 4), dim3(256), 0, stream,
                       vb, offs, se, sw, scal, rstat, out);
}

// Round 4
// 470.726 us; speedup vs baseline: 1.2552x; 1.2552x over previous
//
#include <hip/hip_runtime.h>
#include <math.h>

#define N_NODES 100000
#define N_EDGES 1600000
#define DIM 128
#define EIGD 32
#define CS_EPS 1e-8f

#define B1 1024                   // coarse-pass blocks (4/CU)
#define CHUNK 1563                // ceil(N_EDGES / B1)
#define NB 391                    // ceil(N_NODES/256) coarse buckets of 256 rows
#define FCAP 4800                 // LDS staging capacity per bucket (mean 4092, sd 64 -> +11 sd)

// ---- workspace layout (bytes), total 83,619,616 ----
static const size_t OFF_REC    = 0;          // E int2 coarse-sorted records (dead after kf_fine)
static const size_t OFF_SW     = 0;          // E float edge scores (ALIASES rec, written by ks_score)
static const size_t OFF_RSTAT  = 6400000;    // N float4 {m0,z0,m1,z1} (aliases rec tail)
static const size_t OFF_SE     = 12800000;   // E float2 {col_bits, adj} CSR-ordered
static const size_t OFF_GH     = 12800000;   // B1*NB int (aliases se: gh dead before kf_fine writes se)
static const size_t OFF_BSTART = 25600000;   // (NB+1) int
static const size_t OFF_BTOT   = 25601600;   // NB int
static const size_t OFF_GPART  = 25603200;   // B1 float4
static const size_t OFF_OFFS   = 25619584;   // N+1 int (padded)
static const size_t OFF_SCAL   = 26019600;   // 4 float
static const size_t OFF_KB     = 26019616;   // N*128 bf16 = 25.6 MB
static const size_t OFF_VB     = 51619616;   // N*128 bf16 = 25.6 MB
static const size_t OFF_EB     = 77219616;   // N*32  bf16 = 6.4 MB

__device__ __forceinline__ unsigned short f2bf(float f) {
    unsigned u = __float_as_uint(f);
    unsigned r = (u + 0x7fffu + ((u >> 16) & 1u)) >> 16;   // RNE
    return (unsigned short)r;
}
__device__ __forceinline__ float blo(unsigned w) { return __uint_as_float(w << 16); }
__device__ __forceinline__ float bhi(unsigned w) { return __uint_as_float(w & 0xffff0000u); }

#define K4C 3200000   // N*128/4 float4s in k (and v)
#define E4C 800000    // N*32/4  float4s in eigs

// Convert k, v, eigs to bf16 staging arrays (halves gather line traffic).
__global__ void __launch_bounds__(256) ka_cvt(
        const float* __restrict__ k, const float* __restrict__ v,
        const float* __restrict__ eigs,
        ushort* __restrict__ kb, ushort* __restrict__ vb,
        ushort* __restrict__ eb) {
    int i = blockIdx.x * blockDim.x + threadIdx.x;
    const float* src; ushort* dst; int j;
    if (i < K4C)            { src = k;    dst = kb; j = i; }
    else if (i < 2 * K4C)   { src = v;    dst = vb; j = i - K4C; }
    else if (i < 2*K4C+E4C) { src = eigs; dst = eb; j = i - 2 * K4C; }
    else return;
    float4 f = ((const float4*)src)[j];
    ushort4 o;
    o.x = f2bf(f.x); o.y = f2bf(f.y); o.z = f2bf(f.z); o.w = f2bf(f.w);
    ((ushort4*)dst)[j] = o;
}

// Coarse histogram over row>>8 + cosine-sim partial sums. No global atomics.
__global__ void __launch_bounds__(256) kb_hist(
        const int* __restrict__ row, const int* __restrict__ col,
        const float* __restrict__ motif_w, const int* __restrict__ motif_ids,
        int* __restrict__ gh, float4* __restrict__ gpart) {
    __shared__ int hist[NB];
    __shared__ float wlds[64];
    __shared__ float red[3][4];
    const int t = threadIdx.x, b = blockIdx.x;
    for (int i = t; i < NB; i += 256) hist[i] = 0;
    if (t < 64) wlds[t] = motif_w[t];
    __syncthreads();

    const int e0 = b * CHUNK, e1 = min(N_EDGES, e0 + CHUNK);
    float sab = 0.f, saa = 0.f, sbb = 0.f;
    for (int e = e0 + t; e < e1; e += 256) {
        int r = row[e], c = col[e];
        atomicAdd(&hist[r >> 8], 1);
        float mr = wlds[motif_ids[r]], mc = wlds[motif_ids[c]];
        sab += mr * mc; saa += mr * mr; sbb += mc * mc;
    }
#pragma unroll
    for (int off = 32; off >= 1; off >>= 1) {
        sab += __shfl_xor(sab, off);
        saa += __shfl_xor(saa, off);
        sbb += __shfl_xor(sbb, off);
    }
    int lane = t & 63, wid = t >> 6;
    if (lane == 0) { red[0][wid] = sab; red[1][wid] = saa; red[2][wid] = sbb; }
    __syncthreads();
    if (t == 0) {
        float a = 0.f, bb = 0.f, cc = 0.f;
#pragma unroll
        for (int i = 0; i < 4; i++) { a += red[0][i]; bb += red[1][i]; cc += red[2][i]; }
        gpart[b] = make_float4(a, bb, cc, 0.f);
    }
    __syncthreads();
    for (int i = t; i < NB; i += 256) gh[b * NB + i] = hist[i];
}

// Parallel column scan: one block per bucket, scans its B1-long gh column
// in-place to exclusive prefixes, writes column total.
__global__ void __launch_bounds__(256) ks_scanA(
        int* __restrict__ gh, int* __restrict__ btot) {
    const int colb = blockIdx.x;   // bucket id
    const int t = threadIdx.x;
    int v0 = gh[(t * 4 + 0) * NB + colb];
    int v1 = gh[(t * 4 + 1) * NB + colb];
    int v2 = gh[(t * 4 + 2) * NB + colb];
    int v3 = gh[(t * 4 + 3) * NB + colb];
    int tot4 = v0 + v1 + v2 + v3;
    __shared__ int sc[256];
    sc[t] = tot4;
    __syncthreads();
    for (int off = 1; off < 256; off <<= 1) {
        int w = (t >= off) ? sc[t - off] : 0;
        __syncthreads();
        sc[t] += w;
        __syncthreads();
    }
    int excl = sc[t] - tot4;
    gh[(t * 4 + 0) * NB + colb] = excl;
    gh[(t * 4 + 1) * NB + colb] = excl + v0;
    gh[(t * 4 + 2) * NB + colb] = excl + v0 + v1;
    gh[(t * 4 + 3) * NB + colb] = excl + v0 + v1 + v2;
    if (t == 255) btot[colb] = excl + tot4;
}

// One small block: scan bucket totals -> bstart, cosine reduce -> scal.
__global__ void __launch_bounds__(512) ks_scanB(
        const int* __restrict__ btot, int* __restrict__ bstart,
        const float4* __restrict__ gpart, const float* __restrict__ gamma,
        float* __restrict__ scal, int* __restrict__ offs) {
    const int t = threadIdx.x;
    __shared__ int tot[512];
    int my = (t < NB) ? btot[t] : 0;
    tot[t] = my;
    __syncthreads();
    for (int off = 1; off < 512; off <<= 1) {
        int v = (t >= off) ? tot[t - off] : 0;
        __syncthreads();
        tot[t] += v;
        __syncthreads();
    }
    if (t < NB) bstart[t] = tot[t] - my;
    if (t == NB - 1) {
        bstart[NB] = tot[t];
        offs[N_NODES] = tot[t];
    }

    float4 g0 = gpart[t];
    float4 g1 = gpart[t + 512];
    float sab = g0.x + g1.x, saa = g0.y + g1.y, sbb = g0.z + g1.z;
#pragma unroll
    for (int off = 32; off >= 1; off >>= 1) {
        sab += __shfl_xor(sab, off);
        saa += __shfl_xor(saa, off);
        sbb += __shfl_xor(sbb, off);
    }
    __shared__ float red[3][8];
    int lane = t & 63, wid = t >> 6;
    if (lane == 0) { red[0][wid] = sab; red[1][wid] = saa; red[2][wid] = sbb; }
    __syncthreads();
    if (t == 0) {
        float a = 0.f, bb = 0.f, cc = 0.f;
#pragma unroll
        for (int i = 0; i < 8; i++) { a += red[0][i]; bb += red[1][i]; cc += red[2][i]; }
        float na = sqrtf(bb); if (na < CS_EPS) na = CS_EPS;
        float nb2 = sqrtf(cc); if (nb2 < CS_EPS) nb2 = CS_EPS;
        scal[0] = gamma[0] * (a / (na * nb2));
    }
}

// Coarse scatter into bucket-sorted records; LDS cursors only.
__global__ void __launch_bounds__(256) kd_coarse(
        const int* __restrict__ row, const int* __restrict__ col,
        const float* __restrict__ adj, const int* __restrict__ gh,
        const int* __restrict__ bstart, int2* __restrict__ rec) {
    __shared__ int cur[NB];
    const int t = threadIdx.x, b = blockIdx.x;
    for (int i = t; i < NB; i += 256) cur[i] = bstart[i] + gh[b * NB + i];
    __syncthreads();
    const int e0 = b * CHUNK, e1 = min(N_EDGES, e0 + CHUNK);
    for (int e = e0 + t; e < e1; e += 256) {
        int r = row[e];
        int pos = atomicAdd(&cur[r >> 8], 1);
        rec[pos] = make_int2(col[e] | ((r & 255) << 17), __float_as_int(adj[e]));
    }
}

// Fine sort within each bucket (256 rows), LDS-staged:
// single global read of rec (staged to LDS), in-LDS scatter to sorted order,
// coalesced se write. Global-path fallback if a bucket exceeds FCAP.
__global__ void __launch_bounds__(256) kf_fine(
        const int2* __restrict__ rec, const int* __restrict__ bstart,
        int* __restrict__ offs, float2* __restrict__ se) {
    __shared__ int hist[256], sc[256], cur[256];
    __shared__ int2 buf[FCAP];    // load-order staging
    __shared__ int2 buf2[FCAP];   // sorted order
    const int t = threadIdx.x, b = blockIdx.x;
    hist[t] = 0;
    __syncthreads();
    const int s = bstart[b], e1 = bstart[b + 1];
    const int cnt = e1 - s;
    const bool lds = (cnt <= FCAP);
    if (lds) {
        for (int i = t; i < cnt; i += 256) {
            int2 rc = rec[s + i];
            buf[i] = rc;
            atomicAdd(&hist[(rc.x >> 17) & 255], 1);
        }
    } else {
        for (int i = t; i < cnt; i += 256)
            atomicAdd(&hist[(rec[s + i].x >> 17) & 255], 1);
    }
    __syncthreads();
    int v = hist[t];
    sc[t] = v;
    __syncthreads();
    for (int off = 1; off < 256; off <<= 1) {
        int w = (t >= off) ? sc[t - off] : 0;
        __syncthreads();
        sc[t] += w;
        __syncthreads();
    }
    int excl = sc[t] - v;
    int rowg = b * 256 + t;
    if (rowg < N_NODES) offs[rowg] = s + excl;
    cur[t] = lds ? excl : (s + excl);
    __syncthreads();
    if (lds) {
        for (int i = t; i < cnt; i += 256) {
            int2 rc = buf[i];
            int rl = (rc.x >> 17) & 255;
            int pos = atomicAdd(&cur[rl], 1);
            buf2[pos] = make_int2(rc.x & 0x1FFFF, rc.y);
        }
        __syncthreads();
        for (int i = t; i < cnt; i += 256) {
            int2 o = buf2[i];
            se[s + i] = make_float2(__int_as_float(o.x), __int_as_float(o.y));
        }
    } else {
        for (int i = t; i < cnt; i += 256) {
            int2 rc = rec[s + i];
            int rl = (rc.x >> 17) & 255;
            int pos = atomicAdd(&cur[rl], 1);
            se[pos] = make_float2(__int_as_float(rc.x & 0x1FFFF), __int_as_float(rc.y));
        }
    }
}

// Pass A: scores only. Gathers kb+eb; writes per-edge s0 to sw and per-row
// {m0,z0,m1,z1} to rowstat. Low VGPR, loads fully predicated.
__global__ void __launch_bounds__(256) ks_score(
        const float* __restrict__ q, const ushort* __restrict__ kb,
        const ushort* __restrict__ eb,
        const float* __restrict__ lambda0, const int* __restrict__ offs,
        const float2* __restrict__ se, const float* __restrict__ scal,
        float* __restrict__ sw, float4* __restrict__ rowstat) {
    const int tid  = threadIdx.x;
    const int lane = tid & 63;
    const int wid  = tid >> 6;
    const int r = blockIdx.x * 4 + wid;
    if (r >= N_NODES) return;
    const int l16 = lane & 15;
    const int grp = lane >> 4;
    const float inv_sqrt_d = 0.08838834764831843f; // 1/sqrt(128)

    const int start = offs[r], end = offs[r + 1];
    if (end == start) return;   // empty row: rowstat never read by kpv

    const float el0 = __expf(lambda0[0]);
    const float cs  = scal[0];

    const float4* qp = (const float4*)(q + (size_t)r * DIM);
    const float4 qa = qp[l16 * 2];
    const float4 qc = qp[l16 * 2 + 1];
    const unsigned erw = *(const unsigned*)(eb + (size_t)r * EIGD + l16 * 2);
    const float er0 = blo(erw), er1 = bhi(erw);

    const float NEG = -1e30f;   // finite sentinel: exp underflows to 0, no NaN
    float m0 = NEG, z0 = 0.f, m1 = NEG, z1 = 0.f;

    // se prefetch depth-1, predicated per group
    float2 ea_c = make_float2(0.f, 0.f);
    if (start + grp < end) ea_c = se[start + grp];

    for (int base = start; base < end; base += 4) {
        const int e = base + grp;
        const bool act = e < end;                     // group-uniform
        float2 ea_n = make_float2(0.f, 0.f);
        if (base + 4 + grp < end) ea_n = se[base + 4 + grp];

        float s0p = 0.f;
        if (act) {
            int c = __float_as_int(ea_c.x);
            const uint4 kw = *(const uint4*)(kb + (size_t)c * DIM + l16 * 8);
            const unsigned ecw = *(const unsigned*)(eb + (size_t)c * EIGD + l16 * 2);
            float x;
            x = qa.x * blo(kw.x);
            x = fmaf(qa.y, bhi(kw.x), x);
            x = fmaf(qa.z, blo(kw.y), x);
            x = fmaf(qa.w, bhi(kw.y), x);
            x = fmaf(qc.x, blo(kw.z), x);
            x = fmaf(qc.y, bhi(kw.z), x);
            x = fmaf(qc.z, blo(kw.w), x);
            x = fmaf(qc.w, bhi(kw.w), x);
            float y = er0 * blo(ecw) + er1 * bhi(ecw);
            s0p = fmaf(el0, y, x * inv_sqrt_d);
        }
        // butterfly within the 16-lane group -> group-uniform score
#pragma unroll
        for (int off = 8; off >= 1; off >>= 1) s0p += __shfl_xor(s0p, off);

        if (act) {
            if (l16 == 0) sw[e] = s0p;   // 4 consecutive floats per wave-iter
            float nm0 = fmaxf(m0, s0p);
            z0 = z0 * __expf(m0 - nm0) + __expf(s0p - nm0);
            m0 = nm0;
            float s1 = cs * ea_c.y;
            float nm1 = fmaxf(m1, s1);
            z1 = z1 * __expf(m1 - nm1) + __expf(s1 - nm1);
            m1 = nm1;
        }
        ea_c = ea_n;
    }

    // merge the 4 groups' (m,z) pairs
#pragma unroll
    for (int off = 16; off <= 32; off <<= 1) {
        float mo = __shfl_xor(m0, off), zo = __shfl_xor(z0, off);
        float M = fmaxf(m0, mo);
        z0 = z0 * __expf(m0 - M) + zo * __expf(mo - M);
        m0 = M;
        float mo1 = __shfl_xor(m1, off), zo1 = __shfl_xor(z1, off);
        float M1 = fmaxf(m1, mo1);
        z1 = z1 * __expf(m1 - M1) + zo1 * __expf(mo1 - M1);
        m1 = M1;
    }
    if (lane == 0) rowstat[r] = make_float4(m0, z0, m1, z1);
}

// Pass B: PV only. Gathers vb; final weights from sw + rowstat (exact
// two-pass softmax).
__global__ void __launch_bounds__(256) kpv(
        const ushort* __restrict__ vb, const int* __restrict__ offs,
        const float2* __restrict__ se, const float* __restrict__ sw,
        const float* __restrict__ scal, const float4* __restrict__ rowstat,
        float* __restrict__ out) {
    const int tid  = threadIdx.x;
    const int lane = tid & 63;
    const int wid  = tid >> 6;
    const int r = blockIdx.x * 4 + wid;
    if (r >= N_NODES) return;
    const int l16 = lane & 15;
    const int grp = lane >> 4;

    float2* outp = (float2*)(out + (size_t)r * DIM);
    const int start = offs[r], end = offs[r + 1];
    if (end == start) {
        outp[l16 * 4 + grp] = make_float2(0.f, 0.f);
        return;
    }
    const float cs = scal[0];
    const float4 st = rowstat[r];
    const float m0 = st.x, iz0 = 0.5f / st.y;
    const float m1 = st.z, iz1 = 0.5f / st.w;

    float a[8];
#pragma unroll
    for (int j = 0; j < 8; j++) a[j] = 0.f;

    float2 ea_c = make_float2(0.f, 0.f);
    float  sw_c = 0.f;
    if (start + grp < end) { ea_c = se[start + grp]; sw_c = sw[start + grp]; }

    for (int base = start; base < end; base += 4) {
        const int e = base + grp;
        const bool act = e < end;
        float2 ea_n = make_float2(0.f, 0.f);
        float  sw_n = 0.f;
        if (base + 4 + grp < end) { ea_n = se[base + 4 + grp]; sw_n = sw[base + 4 + grp]; }

        if (act) {
            int c = __float_as_int(ea_c.x);
            const uint4 vw = *(const uint4*)(vb + (size_t)c * DIM + l16 * 8);
            float u = __expf(sw_c - m0) * iz0 + __expf(cs * ea_c.y - m1) * iz1;
            a[0] = fmaf(u, blo(vw.x), a[0]); a[1] = fmaf(u, bhi(vw.x), a[1]);
            a[2] = fmaf(u, blo(vw.y), a[2]); a[3] = fmaf(u, bhi(vw.y), a[3]);
            a[4] = fmaf(u, blo(vw.z), a[4]); a[5] = fmaf(u, bhi(vw.z), a[5]);
            a[6] = fmaf(u, blo(vw.w), a[6]); a[7] = fmaf(u, bhi(vw.w), a[7]);
        }
        ea_c = ea_n; sw_c = sw_n;
    }

    // plain sum across the 4 groups (weights already final)
#pragma unroll
    for (int off = 16; off <= 32; off <<= 1) {
#pragma unroll
        for (int j = 0; j < 8; j++) a[j] += __shfl_xor(a[j], off);
    }
    float b0 = grp == 0 ? a[0] : grp == 1 ? a[2] : grp == 2 ? a[4] : a[6];
    float b1 = grp == 0 ? a[1] : grp == 1 ? a[3] : grp == 2 ? a[5] : a[7];
    outp[l16 * 4 + grp] = make_float2(b0, b1);
}

extern "C" void kernel_launch(void* const* d_in, const int* in_sizes, int n_in,
                              void* d_out, int out_size, void* d_ws, size_t ws_size,
                              hipStream_t stream) {
    const float* q        = (const float*)d_in[0];
    const float* k        = (const float*)d_in[1];
    const float* v        = (const float*)d_in[2];
    const float* eigs     = (const float*)d_in[3];
    const float* adj      = (const float*)d_in[4];
    const float* lambda0  = (const float*)d_in[5];
    const float* gamma    = (const float*)d_in[6];
    const float* motif_w  = (const float*)d_in[7];
    const int*   row      = (const int*)d_in[8];
    const int*   col      = (const int*)d_in[9];
    const int*   motif_ids= (const int*)d_in[10];
    float* out = (float*)d_out;

    char* ws = (char*)d_ws;
    int2*   rec    = (int2*)(ws + OFF_REC);
    float*  sw     = (float*)(ws + OFF_SW);      // aliases rec (dead after kf_fine)
    float4* rstat  = (float4*)(ws + OFF_RSTAT);  // aliases rec tail
    float2* se     = (float2*)(ws + OFF_SE);
    int*    gh     = (int*)(ws + OFF_GH);        // aliases se (dead before se written)
    int*    bstart = (int*)(ws + OFF_BSTART);
    int*    btot   = (int*)(ws + OFF_BTOT);
    float4* gpart  = (float4*)(ws + OFF_GPART);
    int*    offs   = (int*)(ws + OFF_OFFS);
    float*  scal   = (float*)(ws + OFF_SCAL);
    ushort* kb     = (ushort*)(ws + OFF_KB);
    ushort* vb     = (ushort*)(ws + OFF_VB);
    ushort* eb     = (ushort*)(ws + OFF_EB);

    hipLaunchKernelGGL(ka_cvt, dim3((2 * K4C + E4C + 255) / 256), dim3(256), 0, stream,
                       k, v, eigs, kb, vb, eb);
    hipLaunchKernelGGL(kb_hist, dim3(B1), dim3(256), 0, stream,
                       row, col, motif_w, motif_ids, gh, gpart);
    hipLaunchKernelGGL(ks_scanA, dim3(NB), dim3(256), 0, stream,
                       gh, btot);
    hipLaunchKernelGGL(ks_scanB, dim3(1), dim3(512), 0, stream,
                       btot, bstart, gpart, gamma, scal, offs);
    hipLaunchKernelGGL(kd_coarse, dim3(B1), dim3(256), 0, stream,
                       row, col, adj, gh, bstart, rec);
    hipLaunchKernelGGL(kf_fine, dim3(NB), dim3(256), 0, stream,
                       rec, bstart, offs, se);
    hipLaunchKernelGGL(ks_score, dim3((N_NODES + 3) / 4), dim3(256), 0, stream,
                       q, kb, eb, lambda0, offs, se, scal, sw, rstat);
    hipLaunchKernelGGL(kpv, dim3((N_NODES + 3) / 4), dim3(256), 0, stream,
                       vb, offs, se, sw, scal, rstat, out);
}